// Round 6
// baseline (281.674 us; speedup 1.0000x reference)
//
#include <hip/hip_runtime.h>
#include <hip/hip_bf16.h>
#include <math.h>

#define NN 20000
#define DEGV 16
#define CINV 128
#define TSTEPS 3
#define HIDV 128

typedef float f32x4 __attribute__((ext_vector_type(4)));
typedef short s16x8 __attribute__((ext_vector_type(8)));

#define MFMA16(a, b, c) __builtin_amdgcn_mfma_f32_16x16x32_bf16(a, b, c, 0, 0, 0)

static __device__ __forceinline__ short f2bf(float x) {
    __hip_bfloat16 h = __float2bfloat16(x);
    return *reinterpret_cast<short*>(&h);
}

// ---------------------------------------------------------------------------
// Kernel 1: P[s][n][j] = sum_k v[n][k] * W1[(s*128+k)*64 + j]   (slot-major)
// also init base[n][j] = P[0][n][j] + b1[j], walk_idx[0][n] = n
// ---------------------------------------------------------------------------
__global__ __launch_bounds__(256) void k_precompute(
    const float* __restrict__ v, const float* __restrict__ W1,
    const float* __restrict__ b1,
    float* __restrict__ P, float* __restrict__ base, int* __restrict__ walk_idx)
{
    __shared__ float vt[16][132];
    int nb = blockIdx.x * 16;
    for (int idx = threadIdx.x; idx < 16 * 128; idx += 256) {
        int nl = idx >> 7, k = idx & 127;
        int n = nb + nl;
        vt[nl][k] = (n < NN) ? v[n * 128 + k] : 0.f;
    }
    __syncthreads();
    int s = threadIdx.x >> 6;
    int j = threadIdx.x & 63;
    double acc[16];
#pragma unroll
    for (int nl = 0; nl < 16; ++nl) acc[nl] = 0.0;
    for (int k = 0; k < 128; ++k) {
        double w = (double)W1[(s * 128 + k) * 64 + j];
#pragma unroll
        for (int nl = 0; nl < 16; ++nl)
            acc[nl] = fma((double)vt[nl][k], w, acc[nl]);
    }
    for (int nl = 0; nl < 16; ++nl) {
        int n = nb + nl;
        if (n < NN) {
            float pv = (float)acc[nl];
            P[(size_t)s * NN * 64 + n * 64 + j] = pv;
            if (s == 0) {
                base[n * 64 + j] = pv + b1[j];
                if (j == 0) walk_idx[n] = n;
            }
        }
    }
}

// ---------------------------------------------------------------------------
// Kernel 2: one walk selection step. One 64-lane wave per node.
// ---------------------------------------------------------------------------
__global__ __launch_bounds__(256) void k_walk_step(
    const float* __restrict__ P, float* __restrict__ base,
    const int* __restrict__ dst, const float* __restrict__ W2,
    const float* __restrict__ b2, const float* __restrict__ noise,
    int* __restrict__ walk_idx, int t)
{
    int wave = threadIdx.x >> 6;
    int lane = threadIdx.x & 63;
    int n = blockIdx.x * 4 + wave;
    if (n >= NN) return;

    int wl = walk_idx[t * NN + n];
    int d = lane >> 2, sub = lane & 3;
    int cand = dst[wl * DEGV + d];

    const float* Pslice = P + (size_t)(t + 1) * NN * 64;
    const float4* b4 = (const float4*)(base + (size_t)n * 64);
    const float4* p4 = (const float4*)(Pslice + (size_t)cand * 64);
    const float4* w4 = (const float4*)W2;

    double acc = 0.0;
#pragma unroll
    for (int k = 0; k < 4; ++k) {
        float4 bb = b4[sub * 4 + k];
        float4 pp = p4[sub * 4 + k];
        float4 ww = w4[sub * 4 + k];
        acc += (double)fmaxf(bb.x + pp.x, 0.f) * (double)ww.x;
        acc += (double)fmaxf(bb.y + pp.y, 0.f) * (double)ww.y;
        acc += (double)fmaxf(bb.z + pp.z, 0.f) * (double)ww.z;
        acc += (double)fmaxf(bb.w + pp.w, 0.f) * (double)ww.w;
    }
    acc += __shfl_xor(acc, 1);
    acc += __shfl_xor(acc, 2);
    double logp = acc + (double)b2[0];

    double m = logp;
    for (int mask = 4; mask < 64; mask <<= 1) m = fmax(m, __shfl_xor(m, mask));
    double e = exp(logp - m);
    double ssum = e;
    for (int mask = 4; mask < 64; mask <<= 1) ssum += __shfl_xor(ssum, mask);
    double norm = m + log(ssum);

    double wp = exp(logp - norm) +
                0.01 * (double)noise[((size_t)t * NN + n) * DEGV + d];

    int bd = d;
    double bwp = wp;
    for (int mask = 4; mask < 64; mask <<= 1) {
        double owp = __shfl_xor(bwp, mask);
        int od = __shfl_xor(bd, mask);
        if (owp > bwp || (owp == bwp && od < bd)) { bwp = owp; bd = od; }
    }
    int sel = dst[wl * DEGV + bd];

    base[(size_t)n * 64 + lane] += Pslice[(size_t)sel * 64 + lane];
    if (lane == 0) walk_idx[(t + 1) * NN + n] = sel;
}

// ---------------------------------------------------------------------------
// Kernel 3: convert weights to bf16 (Wih, Whh row-major; Wout transposed)
// ---------------------------------------------------------------------------
__global__ __launch_bounds__(256) void k_convert_w(
    const float* __restrict__ Wih, const float* __restrict__ Whh,
    const float* __restrict__ Wout,
    short* __restrict__ Wihb, short* __restrict__ Whhb, short* __restrict__ WoutTb)
{
    int idx = blockIdx.x * 256 + threadIdx.x;
    if (idx < 49152) {
        Wihb[idx] = f2bf(Wih[idx]);
    } else if (idx < 98304) {
        int e = idx - 49152;
        Whhb[e] = f2bf(Whh[e]);
    } else if (idx < 114688) {
        int e = idx - 98304;
        int o = e >> 7, k = e & 127;
        WoutTb[e] = f2bf(Wout[k * 128 + o]);   // WoutT[o][k]
    }
}

// ---------------------------------------------------------------------------
// Kernel 4: fused GRU (4 steps) + output projection, MFMA bf16.
// Block = 256 threads (4 waves), 32 NODES per block (two 16-node A-groups
// sharing every B-fragment load). Grid = 625 -> 3 blocks/CU, one round.
// Wave w owns gate-column tiles {2w, 2w+1} and o-tiles {2w, 2w+1}.
// A-frag: row=lane&15 (node within group), k=(lane>>4)*8 per K=32 chunk.
// C/D layout (verified): row=(lane>>4)*4+reg, col=lane&15.
// ---------------------------------------------------------------------------
__global__ __launch_bounds__(256, 3) void k_gru_fused(
    const float* __restrict__ v, const int* __restrict__ widx,
    const short* __restrict__ Wihb, const short* __restrict__ Whhb,
    const short* __restrict__ WoutTb,
    const float* __restrict__ bih, const float* __restrict__ bhh,
    const float* __restrict__ bout, float* __restrict__ out)
{
    __shared__ short x_bf[32][136];
    __shared__ short h_bf[32][136];
    int tid = threadIdx.x;
    int w = tid >> 6, lane = tid & 63;
    int c = lane & 15, q = lane >> 4;
    int nb = blockIdx.x * 32;

    // hoisted biases for this wave's two tiles
    float b_r[2], b_z[2], b_in[2], b_hn[2];
#pragma unroll
    for (int nt = 0; nt < 2; ++nt) {
        int u = (2 * w + nt) * 16 + c;
        b_r[nt]  = bih[u] + bhh[u];
        b_z[nt]  = bih[128 + u] + bhh[128 + u];
        b_in[nt] = bih[256 + u];
        b_hn[nt] = bhh[256 + u];
    }

    float h_reg[2][2][4];        // [group][nt][i]
    s16x8 ah[2][4];
    s16x8 z8 = {0, 0, 0, 0, 0, 0, 0, 0};
#pragma unroll
    for (int g = 0; g < 2; ++g) {
#pragma unroll
        for (int nt = 0; nt < 2; ++nt)
#pragma unroll
            for (int i = 0; i < 4; ++i) h_reg[g][nt][i] = 0.f;
#pragma unroll
        for (int ks = 0; ks < 4; ++ks) ah[g][ks] = z8;
    }

    const short* bi_base = Wihb + c * 128 + q * 8;
    const short* bh_base = Whhb + c * 128 + q * 8;

#pragma unroll 1
    for (int t = 0; t < 1 + TSTEPS; ++t) {
        // ---- gather x_t = v[walk_idx[t]] -> bf16 LDS (32 rows x 16 chunks) ----
#pragma unroll
        for (int rep = 0; rep < 2; ++rep) {
            int row = (tid >> 4) + rep * 16, chunk = tid & 15;
            int src = widx[t * NN + nb + row];
            const float4* vp = (const float4*)(v + (size_t)src * 128 + chunk * 8);
            float4 a = vp[0], b = vp[1];
            s16x8 xv;
            xv[0] = f2bf(a.x); xv[1] = f2bf(a.y); xv[2] = f2bf(a.z); xv[3] = f2bf(a.w);
            xv[4] = f2bf(b.x); xv[5] = f2bf(b.y); xv[6] = f2bf(b.z); xv[7] = f2bf(b.w);
            *(s16x8*)&x_bf[row][chunk * 8] = xv;
        }
        __syncthreads();

        s16x8 ax[2][4];
#pragma unroll
        for (int g = 0; g < 2; ++g)
#pragma unroll
            for (int ks = 0; ks < 4; ++ks)
                ax[g][ks] = *(const s16x8*)&x_bf[g * 16 + c][ks * 32 + q * 8];

        // ---- this wave's two gate tiles, both node groups share B-frags ----
#pragma unroll
        for (int nt = 0; nt < 2; ++nt) {
            int tr = 2 * w + nt;          // tile index (0..7)
            f32x4 zf = {0.f, 0.f, 0.f, 0.f};
            f32x4 aR[2] = {zf, zf}, aZ[2] = {zf, zf}, aIN[2] = {zf, zf}, aHN[2] = {zf, zf};
#pragma unroll
            for (int ks = 0; ks < 4; ++ks) {
                s16x8 biR = *(const s16x8*)(bi_base + tr * 2048 + ks * 32);
                s16x8 bhR = *(const s16x8*)(bh_base + tr * 2048 + ks * 32);
                s16x8 biZ = *(const s16x8*)(bi_base + (8 + tr) * 2048 + ks * 32);
                s16x8 bhZ = *(const s16x8*)(bh_base + (8 + tr) * 2048 + ks * 32);
                s16x8 biN = *(const s16x8*)(bi_base + (16 + tr) * 2048 + ks * 32);
                s16x8 bhN = *(const s16x8*)(bh_base + (16 + tr) * 2048 + ks * 32);
#pragma unroll
                for (int g = 0; g < 2; ++g) {
                    aR[g]  = MFMA16(ax[g][ks], biR, aR[g]);
                    aR[g]  = MFMA16(ah[g][ks], bhR, aR[g]);
                    aZ[g]  = MFMA16(ax[g][ks], biZ, aZ[g]);
                    aZ[g]  = MFMA16(ah[g][ks], bhZ, aZ[g]);
                    aIN[g] = MFMA16(ax[g][ks], biN, aIN[g]);
                    aHN[g] = MFMA16(ah[g][ks], bhN, aHN[g]);
                }
            }
#pragma unroll
            for (int g = 0; g < 2; ++g)
#pragma unroll
                for (int i = 0; i < 4; ++i) {
                    float r = 1.f / (1.f + expf(-(aR[g][i] + b_r[nt])));
                    float z = 1.f / (1.f + expf(-(aZ[g][i] + b_z[nt])));
                    float ng = tanhf(aIN[g][i] + b_in[nt] + r * (aHN[g][i] + b_hn[nt]));
                    float hn = (1.f - z) * ng + z * h_reg[g][nt][i];
                    h_reg[g][nt][i] = hn;
                    h_bf[g * 16 + q * 4 + i][tr * 16 + c] = f2bf(hn);
                }
        }
        __syncthreads();

        // ---- reload full-h fragments (transposed view) for next step / output ----
#pragma unroll
        for (int g = 0; g < 2; ++g)
#pragma unroll
            for (int ks = 0; ks < 4; ++ks)
                ah[g][ks] = *(const s16x8*)&h_bf[g * 16 + c][ks * 32 + q * 8];
    }

    // ---- output projection: wave w handles EXACTLY o-tiles {2w, 2w+1} ----
    const short* bo_base = WoutTb + c * 128 + q * 8;
#pragma unroll
    for (int nt = 0; nt < 2; ++nt) {
        int ot = 2 * w + nt;              // 0..7 across the 4 waves
        f32x4 zf = {0.f, 0.f, 0.f, 0.f};
        f32x4 acco[2] = {zf, zf};
#pragma unroll
        for (int ks = 0; ks < 4; ++ks) {
            s16x8 bo = *(const s16x8*)(bo_base + ot * 2048 + ks * 32);
#pragma unroll
            for (int g = 0; g < 2; ++g)
                acco[g] = MFMA16(ah[g][ks], bo, acco[g]);
        }
        int o = ot * 16 + c;
        float bb = bout[o];
#pragma unroll
        for (int g = 0; g < 2; ++g)
#pragma unroll
            for (int i = 0; i < 4; ++i)
                out[(size_t)(nb + g * 16 + q * 4 + i) * 128 + o] = acco[g][i] + bb;
    }
}

// ---------------------------------------------------------------------------
extern "C" void kernel_launch(void* const* d_in, const int* in_sizes, int n_in,
                              void* d_out, int out_size, void* d_ws, size_t ws_size,
                              hipStream_t stream)
{
    const float* node_attr = (const float*)d_in[0];
    const int*   edge_index = (const int*)d_in[1];
    const float* W1  = (const float*)d_in[3];
    const float* b1  = (const float*)d_in[4];
    const float* W2  = (const float*)d_in[5];
    const float* b2  = (const float*)d_in[6];
    const float* Wih = (const float*)d_in[7];
    const float* Whh = (const float*)d_in[8];
    const float* bih = (const float*)d_in[9];
    const float* bhh = (const float*)d_in[10];
    const float* Wout = (const float*)d_in[11];
    const float* bout = (const float*)d_in[12];
    const float* noise = (const float*)d_in[13];

    const int* dst = edge_index + (size_t)NN * DEGV;

    char* ws = (char*)d_ws;
    size_t offP    = 0;                               // 4*N*64 f32 = 20.48 MB
    size_t offBase = offP + (size_t)4 * NN * 64 * 4;  // N*64 f32   =  5.12 MB
    size_t offW    = offBase + (size_t)NN * 64 * 4;   // bf16 weights
    size_t offWidx = offW + (size_t)(2 * 49152 + 16384) * 2;
    float* P    = (float*)(ws + offP);
    float* base = (float*)(ws + offBase);
    short* Wihb   = (short*)(ws + offW);              // 384*128*2 = 96 KB
    short* Whhb   = Wihb + 384 * 128;
    short* WoutTb = Whhb + 384 * 128;                 // 128*128*2 = 32 KB
    int*   widx = (int*)(ws + offWidx);               // 4*N int

    dim3 blk(256);
    k_convert_w<<<dim3(448), blk, 0, stream>>>(Wih, Whh, Wout, Wihb, Whhb, WoutTb);
    k_precompute<<<dim3(1250), blk, 0, stream>>>(node_attr, W1, b1, P, base, widx);
    for (int t = 0; t < TSTEPS; ++t)
        k_walk_step<<<dim3(5000), blk, 0, stream>>>(P, base, dst, W2, b2, noise, widx, t);
    k_gru_fused<<<dim3(625), blk, 0, stream>>>(node_attr, widx, Wihb, Whhb, WoutTb,
                                               bih, bhh, bout, (float*)d_out);
}

// Round 7
// 250.647 us; speedup vs baseline: 1.1238x; 1.1238x over previous
//
#include <hip/hip_runtime.h>
#include <hip/hip_bf16.h>
#include <math.h>

#define NN 20000
#define DEGV 16
#define CINV 128
#define TSTEPS 3
#define HIDV 128

typedef float f32x4 __attribute__((ext_vector_type(4)));
typedef short s16x8 __attribute__((ext_vector_type(8)));

#define MFMA16(a, b, c) __builtin_amdgcn_mfma_f32_16x16x32_bf16(a, b, c, 0, 0, 0)

static __device__ __forceinline__ short f2bf(float x) {
    __hip_bfloat16 h = __float2bfloat16(x);
    return *reinterpret_cast<short*>(&h);
}

// ---------------------------------------------------------------------------
// Kernel 1: P[s][n][j] = sum_k v[n][k] * W1[(s*128+k)*64 + j]   (slot-major)
// also init base[n][j] = P[0][n][j] + b1[j], walk_idx[0][n] = n
// ---------------------------------------------------------------------------
__global__ __launch_bounds__(256) void k_precompute(
    const float* __restrict__ v, const float* __restrict__ W1,
    const float* __restrict__ b1,
    float* __restrict__ P, float* __restrict__ base, int* __restrict__ walk_idx)
{
    __shared__ float vt[16][132];
    int nb = blockIdx.x * 16;
    for (int idx = threadIdx.x; idx < 16 * 128; idx += 256) {
        int nl = idx >> 7, k = idx & 127;
        int n = nb + nl;
        vt[nl][k] = (n < NN) ? v[n * 128 + k] : 0.f;
    }
    __syncthreads();
    int s = threadIdx.x >> 6;
    int j = threadIdx.x & 63;
    double acc[16];
#pragma unroll
    for (int nl = 0; nl < 16; ++nl) acc[nl] = 0.0;
    for (int k = 0; k < 128; ++k) {
        double w = (double)W1[(s * 128 + k) * 64 + j];
#pragma unroll
        for (int nl = 0; nl < 16; ++nl)
            acc[nl] = fma((double)vt[nl][k], w, acc[nl]);
    }
    for (int nl = 0; nl < 16; ++nl) {
        int n = nb + nl;
        if (n < NN) {
            float pv = (float)acc[nl];
            P[(size_t)s * NN * 64 + n * 64 + j] = pv;
            if (s == 0) {
                base[n * 64 + j] = pv + b1[j];
                if (j == 0) walk_idx[n] = n;
            }
        }
    }
}

// ---------------------------------------------------------------------------
// Kernel 2: one walk selection step. One 64-lane wave per node.
// ---------------------------------------------------------------------------
__global__ __launch_bounds__(256) void k_walk_step(
    const float* __restrict__ P, float* __restrict__ base,
    const int* __restrict__ dst, const float* __restrict__ W2,
    const float* __restrict__ b2, const float* __restrict__ noise,
    int* __restrict__ walk_idx, int t)
{
    int wave = threadIdx.x >> 6;
    int lane = threadIdx.x & 63;
    int n = blockIdx.x * 4 + wave;
    if (n >= NN) return;

    int wl = walk_idx[t * NN + n];
    int d = lane >> 2, sub = lane & 3;
    int cand = dst[wl * DEGV + d];

    const float* Pslice = P + (size_t)(t + 1) * NN * 64;
    const float4* b4 = (const float4*)(base + (size_t)n * 64);
    const float4* p4 = (const float4*)(Pslice + (size_t)cand * 64);
    const float4* w4 = (const float4*)W2;

    double acc = 0.0;
#pragma unroll
    for (int k = 0; k < 4; ++k) {
        float4 bb = b4[sub * 4 + k];
        float4 pp = p4[sub * 4 + k];
        float4 ww = w4[sub * 4 + k];
        acc += (double)fmaxf(bb.x + pp.x, 0.f) * (double)ww.x;
        acc += (double)fmaxf(bb.y + pp.y, 0.f) * (double)ww.y;
        acc += (double)fmaxf(bb.z + pp.z, 0.f) * (double)ww.z;
        acc += (double)fmaxf(bb.w + pp.w, 0.f) * (double)ww.w;
    }
    acc += __shfl_xor(acc, 1);
    acc += __shfl_xor(acc, 2);
    double logp = acc + (double)b2[0];

    double m = logp;
    for (int mask = 4; mask < 64; mask <<= 1) m = fmax(m, __shfl_xor(m, mask));
    double e = exp(logp - m);
    double ssum = e;
    for (int mask = 4; mask < 64; mask <<= 1) ssum += __shfl_xor(ssum, mask);
    double norm = m + log(ssum);

    double wp = exp(logp - norm) +
                0.01 * (double)noise[((size_t)t * NN + n) * DEGV + d];

    int bd = d;
    double bwp = wp;
    for (int mask = 4; mask < 64; mask <<= 1) {
        double owp = __shfl_xor(bwp, mask);
        int od = __shfl_xor(bd, mask);
        if (owp > bwp || (owp == bwp && od < bd)) { bwp = owp; bd = od; }
    }
    int sel = dst[wl * DEGV + bd];

    base[(size_t)n * 64 + lane] += Pslice[(size_t)sel * 64 + lane];
    if (lane == 0) walk_idx[(t + 1) * NN + n] = sel;
}

// ---------------------------------------------------------------------------
// Kernel 3: convert weights to bf16 (Wih, Whh row-major; Wout transposed)
// ---------------------------------------------------------------------------
__global__ __launch_bounds__(256) void k_convert_w(
    const float* __restrict__ Wih, const float* __restrict__ Whh,
    const float* __restrict__ Wout,
    short* __restrict__ Wihb, short* __restrict__ Whhb, short* __restrict__ WoutTb)
{
    int idx = blockIdx.x * 256 + threadIdx.x;
    if (idx < 49152) {
        Wihb[idx] = f2bf(Wih[idx]);
    } else if (idx < 98304) {
        int e = idx - 49152;
        Whhb[e] = f2bf(Whh[e]);
    } else if (idx < 114688) {
        int e = idx - 98304;
        int o = e >> 7, k = e & 127;
        WoutTb[e] = f2bf(Wout[k * 128 + o]);   // WoutT[o][k]
    }
}

// ---------------------------------------------------------------------------
// Kernel 4: fused GRU (4 steps) + output projection, MFMA bf16.
// Block = 256 threads (4 waves), 32 NODES per block (two 16-node A-groups
// sharing every B-fragment load -> halved per-node L2 weight traffic, 2x ILP).
// Grid = 625. __launch_bounds__(256,2): 256-VGPR budget (live ~170-200,
// no spill; the round-6 (256,3) 170-cap forced an 84-VGPR spilling kernel).
// Wave w owns gate-column tiles {2w, 2w+1} and o-tiles {2w, 2w+1}.
// A-frag: row=lane&15 (node within group), k=(lane>>4)*8 per K=32 chunk.
// C/D layout (verified): row=(lane>>4)*4+reg, col=lane&15.
// ---------------------------------------------------------------------------
__global__ __launch_bounds__(256, 2) void k_gru_fused(
    const float* __restrict__ v, const int* __restrict__ widx,
    const short* __restrict__ Wihb, const short* __restrict__ Whhb,
    const short* __restrict__ WoutTb,
    const float* __restrict__ bih, const float* __restrict__ bhh,
    const float* __restrict__ bout, float* __restrict__ out)
{
    __shared__ short x_bf[32][136];
    __shared__ short h_bf[32][136];
    int tid = threadIdx.x;
    int w = tid >> 6, lane = tid & 63;
    int c = lane & 15, q = lane >> 4;
    int nb = blockIdx.x * 32;

    // hoisted biases for this wave's two tiles
    float b_r[2], b_z[2], b_in[2], b_hn[2];
#pragma unroll
    for (int nt = 0; nt < 2; ++nt) {
        int u = (2 * w + nt) * 16 + c;
        b_r[nt]  = bih[u] + bhh[u];
        b_z[nt]  = bih[128 + u] + bhh[128 + u];
        b_in[nt] = bih[256 + u];
        b_hn[nt] = bhh[256 + u];
    }

    float h_reg[2][2][4];        // [group][nt][i]
    s16x8 ah[2][4];
    s16x8 z8 = {0, 0, 0, 0, 0, 0, 0, 0};
#pragma unroll
    for (int g = 0; g < 2; ++g) {
#pragma unroll
        for (int nt = 0; nt < 2; ++nt)
#pragma unroll
            for (int i = 0; i < 4; ++i) h_reg[g][nt][i] = 0.f;
#pragma unroll
        for (int ks = 0; ks < 4; ++ks) ah[g][ks] = z8;
    }

    const short* bi_base = Wihb + c * 128 + q * 8;
    const short* bh_base = Whhb + c * 128 + q * 8;

#pragma unroll 1
    for (int t = 0; t < 1 + TSTEPS; ++t) {
        // ---- gather x_t = v[walk_idx[t]] -> bf16 LDS (32 rows x 16 chunks) ----
#pragma unroll
        for (int rep = 0; rep < 2; ++rep) {
            int row = (tid >> 4) + rep * 16, chunk = tid & 15;
            int src = widx[t * NN + nb + row];
            const float4* vp = (const float4*)(v + (size_t)src * 128 + chunk * 8);
            float4 a = vp[0], b = vp[1];
            s16x8 xv;
            xv[0] = f2bf(a.x); xv[1] = f2bf(a.y); xv[2] = f2bf(a.z); xv[3] = f2bf(a.w);
            xv[4] = f2bf(b.x); xv[5] = f2bf(b.y); xv[6] = f2bf(b.z); xv[7] = f2bf(b.w);
            *(s16x8*)&x_bf[row][chunk * 8] = xv;
        }
        __syncthreads();

        s16x8 ax[2][4];
#pragma unroll
        for (int g = 0; g < 2; ++g)
#pragma unroll
            for (int ks = 0; ks < 4; ++ks)
                ax[g][ks] = *(const s16x8*)&x_bf[g * 16 + c][ks * 32 + q * 8];

        // ---- this wave's two gate tiles, both node groups share B-frags ----
#pragma unroll
        for (int nt = 0; nt < 2; ++nt) {
            int tr = 2 * w + nt;          // tile index (0..7)
            f32x4 zf = {0.f, 0.f, 0.f, 0.f};
            f32x4 aR[2] = {zf, zf}, aZ[2] = {zf, zf}, aIN[2] = {zf, zf}, aHN[2] = {zf, zf};
#pragma unroll
            for (int ks = 0; ks < 4; ++ks) {
                s16x8 biR = *(const s16x8*)(bi_base + tr * 2048 + ks * 32);
                s16x8 bhR = *(const s16x8*)(bh_base + tr * 2048 + ks * 32);
                s16x8 biZ = *(const s16x8*)(bi_base + (8 + tr) * 2048 + ks * 32);
                s16x8 bhZ = *(const s16x8*)(bh_base + (8 + tr) * 2048 + ks * 32);
                s16x8 biN = *(const s16x8*)(bi_base + (16 + tr) * 2048 + ks * 32);
                s16x8 bhN = *(const s16x8*)(bh_base + (16 + tr) * 2048 + ks * 32);
#pragma unroll
                for (int g = 0; g < 2; ++g) {
                    aR[g]  = MFMA16(ax[g][ks], biR, aR[g]);
                    aR[g]  = MFMA16(ah[g][ks], bhR, aR[g]);
                    aZ[g]  = MFMA16(ax[g][ks], biZ, aZ[g]);
                    aZ[g]  = MFMA16(ah[g][ks], bhZ, aZ[g]);
                    aIN[g] = MFMA16(ax[g][ks], biN, aIN[g]);
                    aHN[g] = MFMA16(ah[g][ks], bhN, aHN[g]);
                }
            }
#pragma unroll
            for (int g = 0; g < 2; ++g)
#pragma unroll
                for (int i = 0; i < 4; ++i) {
                    float r = 1.f / (1.f + expf(-(aR[g][i] + b_r[nt])));
                    float z = 1.f / (1.f + expf(-(aZ[g][i] + b_z[nt])));
                    float ng = tanhf(aIN[g][i] + b_in[nt] + r * (aHN[g][i] + b_hn[nt]));
                    float hn = (1.f - z) * ng + z * h_reg[g][nt][i];
                    h_reg[g][nt][i] = hn;
                    h_bf[g * 16 + q * 4 + i][tr * 16 + c] = f2bf(hn);
                }
        }
        __syncthreads();

        // ---- reload full-h fragments (transposed view) for next step / output ----
#pragma unroll
        for (int g = 0; g < 2; ++g)
#pragma unroll
            for (int ks = 0; ks < 4; ++ks)
                ah[g][ks] = *(const s16x8*)&h_bf[g * 16 + c][ks * 32 + q * 8];
    }

    // ---- output projection: wave w handles EXACTLY o-tiles {2w, 2w+1} ----
    const short* bo_base = WoutTb + c * 128 + q * 8;
#pragma unroll
    for (int nt = 0; nt < 2; ++nt) {
        int ot = 2 * w + nt;              // 0..7 across the 4 waves
        f32x4 zf = {0.f, 0.f, 0.f, 0.f};
        f32x4 acco[2] = {zf, zf};
#pragma unroll
        for (int ks = 0; ks < 4; ++ks) {
            s16x8 bo = *(const s16x8*)(bo_base + ot * 2048 + ks * 32);
#pragma unroll
            for (int g = 0; g < 2; ++g)
                acco[g] = MFMA16(ah[g][ks], bo, acco[g]);
        }
        int o = ot * 16 + c;
        float bb = bout[o];
#pragma unroll
        for (int g = 0; g < 2; ++g)
#pragma unroll
            for (int i = 0; i < 4; ++i)
                out[(size_t)(nb + g * 16 + q * 4 + i) * 128 + o] = acco[g][i] + bb;
    }
}

// ---------------------------------------------------------------------------
extern "C" void kernel_launch(void* const* d_in, const int* in_sizes, int n_in,
                              void* d_out, int out_size, void* d_ws, size_t ws_size,
                              hipStream_t stream)
{
    const float* node_attr = (const float*)d_in[0];
    const int*   edge_index = (const int*)d_in[1];
    const float* W1  = (const float*)d_in[3];
    const float* b1  = (const float*)d_in[4];
    const float* W2  = (const float*)d_in[5];
    const float* b2  = (const float*)d_in[6];
    const float* Wih = (const float*)d_in[7];
    const float* Whh = (const float*)d_in[8];
    const float* bih = (const float*)d_in[9];
    const float* bhh = (const float*)d_in[10];
    const float* Wout = (const float*)d_in[11];
    const float* bout = (const float*)d_in[12];
    const float* noise = (const float*)d_in[13];

    const int* dst = edge_index + (size_t)NN * DEGV;

    char* ws = (char*)d_ws;
    size_t offP    = 0;                               // 4*N*64 f32 = 20.48 MB
    size_t offBase = offP + (size_t)4 * NN * 64 * 4;  // N*64 f32   =  5.12 MB
    size_t offW    = offBase + (size_t)NN * 64 * 4;   // bf16 weights
    size_t offWidx = offW + (size_t)(2 * 49152 + 16384) * 2;
    float* P    = (float*)(ws + offP);
    float* base = (float*)(ws + offBase);
    short* Wihb   = (short*)(ws + offW);              // 384*128*2 = 96 KB
    short* Whhb   = Wihb + 384 * 128;
    short* WoutTb = Whhb + 384 * 128;                 // 128*128*2 = 32 KB
    int*   widx = (int*)(ws + offWidx);               // 4*N int

    dim3 blk(256);
    k_convert_w<<<dim3(448), blk, 0, stream>>>(Wih, Whh, Wout, Wihb, Whhb, WoutTb);
    k_precompute<<<dim3(1250), blk, 0, stream>>>(node_attr, W1, b1, P, base, widx);
    for (int t = 0; t < TSTEPS; ++t)
        k_walk_step<<<dim3(5000), blk, 0, stream>>>(P, base, dst, W2, b2, noise, widx, t);
    k_gru_fused<<<dim3(625), blk, 0, stream>>>(node_attr, widx, Wihb, Whhb, WoutTb,
                                               bih, bhh, bout, (float*)d_out);
}

// Round 8
// 222.067 us; speedup vs baseline: 1.2684x; 1.1287x over previous
//
#include <hip/hip_runtime.h>
#include <hip/hip_bf16.h>
#include <math.h>

#define NN 20000
#define DEGV 16
#define CINV 128
#define TSTEPS 3
#define HIDV 128

typedef float f32x4 __attribute__((ext_vector_type(4)));
typedef short s16x8 __attribute__((ext_vector_type(8)));

#define MFMA16(a, b, c) __builtin_amdgcn_mfma_f32_16x16x32_bf16(a, b, c, 0, 0, 0)

static __device__ __forceinline__ short f2bf(float x) {
    __hip_bfloat16 h = __float2bfloat16(x);
    return *reinterpret_cast<short*>(&h);
}

// ---------------------------------------------------------------------------
// Kernel 1: P[s][n][j] = sum_k v[n][k] * W1[(s*128+k)*64 + j]   (slot-major)
// also init base[n][j] = P[0][n][j] + b1[j], walk_idx[0][n] = n
// ---------------------------------------------------------------------------
__global__ __launch_bounds__(256) void k_precompute(
    const float* __restrict__ v, const float* __restrict__ W1,
    const float* __restrict__ b1,
    float* __restrict__ P, float* __restrict__ base, int* __restrict__ walk_idx)
{
    __shared__ float vt[16][132];
    int nb = blockIdx.x * 16;
    for (int idx = threadIdx.x; idx < 16 * 128; idx += 256) {
        int nl = idx >> 7, k = idx & 127;
        int n = nb + nl;
        vt[nl][k] = (n < NN) ? v[n * 128 + k] : 0.f;
    }
    __syncthreads();
    int s = threadIdx.x >> 6;
    int j = threadIdx.x & 63;
    double acc[16];
#pragma unroll
    for (int nl = 0; nl < 16; ++nl) acc[nl] = 0.0;
    for (int k = 0; k < 128; ++k) {
        double w = (double)W1[(s * 128 + k) * 64 + j];
#pragma unroll
        for (int nl = 0; nl < 16; ++nl)
            acc[nl] = fma((double)vt[nl][k], w, acc[nl]);
    }
    for (int nl = 0; nl < 16; ++nl) {
        int n = nb + nl;
        if (n < NN) {
            float pv = (float)acc[nl];
            P[(size_t)s * NN * 64 + n * 64 + j] = pv;
            if (s == 0) {
                base[n * 64 + j] = pv + b1[j];
                if (j == 0) walk_idx[n] = n;
            }
        }
    }
}

// ---------------------------------------------------------------------------
// Kernel 2: one walk selection step. One 64-lane wave per node.
// ---------------------------------------------------------------------------
__global__ __launch_bounds__(256) void k_walk_step(
    const float* __restrict__ P, float* __restrict__ base,
    const int* __restrict__ dst, const float* __restrict__ W2,
    const float* __restrict__ b2, const float* __restrict__ noise,
    int* __restrict__ walk_idx, int t)
{
    int wave = threadIdx.x >> 6;
    int lane = threadIdx.x & 63;
    int n = blockIdx.x * 4 + wave;
    if (n >= NN) return;

    int wl = walk_idx[t * NN + n];
    int d = lane >> 2, sub = lane & 3;
    int cand = dst[wl * DEGV + d];

    const float* Pslice = P + (size_t)(t + 1) * NN * 64;
    const float4* b4 = (const float4*)(base + (size_t)n * 64);
    const float4* p4 = (const float4*)(Pslice + (size_t)cand * 64);
    const float4* w4 = (const float4*)W2;

    double acc = 0.0;
#pragma unroll
    for (int k = 0; k < 4; ++k) {
        float4 bb = b4[sub * 4 + k];
        float4 pp = p4[sub * 4 + k];
        float4 ww = w4[sub * 4 + k];
        acc += (double)fmaxf(bb.x + pp.x, 0.f) * (double)ww.x;
        acc += (double)fmaxf(bb.y + pp.y, 0.f) * (double)ww.y;
        acc += (double)fmaxf(bb.z + pp.z, 0.f) * (double)ww.z;
        acc += (double)fmaxf(bb.w + pp.w, 0.f) * (double)ww.w;
    }
    acc += __shfl_xor(acc, 1);
    acc += __shfl_xor(acc, 2);
    double logp = acc + (double)b2[0];

    double m = logp;
    for (int mask = 4; mask < 64; mask <<= 1) m = fmax(m, __shfl_xor(m, mask));
    double e = exp(logp - m);
    double ssum = e;
    for (int mask = 4; mask < 64; mask <<= 1) ssum += __shfl_xor(ssum, mask);
    double norm = m + log(ssum);

    double wp = exp(logp - norm) +
                0.01 * (double)noise[((size_t)t * NN + n) * DEGV + d];

    int bd = d;
    double bwp = wp;
    for (int mask = 4; mask < 64; mask <<= 1) {
        double owp = __shfl_xor(bwp, mask);
        int od = __shfl_xor(bd, mask);
        if (owp > bwp || (owp == bwp && od < bd)) { bwp = owp; bd = od; }
    }
    int sel = dst[wl * DEGV + bd];

    base[(size_t)n * 64 + lane] += Pslice[(size_t)sel * 64 + lane];
    if (lane == 0) walk_idx[(t + 1) * NN + n] = sel;
}

// ---------------------------------------------------------------------------
// Kernel 3: convert weights to bf16 (Wih, Whh row-major; Wout transposed)
// ---------------------------------------------------------------------------
__global__ __launch_bounds__(256) void k_convert_w(
    const float* __restrict__ Wih, const float* __restrict__ Whh,
    const float* __restrict__ Wout,
    short* __restrict__ Wihb, short* __restrict__ Whhb, short* __restrict__ WoutTb)
{
    int idx = blockIdx.x * 256 + threadIdx.x;
    if (idx < 49152) {
        Wihb[idx] = f2bf(Wih[idx]);
    } else if (idx < 98304) {
        int e = idx - 49152;
        Whhb[e] = f2bf(Whh[e]);
    } else if (idx < 114688) {
        int e = idx - 98304;
        int o = e >> 7, k = e & 127;
        WoutTb[e] = f2bf(Wout[k * 128 + o]);   // WoutT[o][k]
    }
}

// ---------------------------------------------------------------------------
// Kernel 4: fused GRU (4 steps) + output projection, MFMA bf16.
// Block = 512 threads (8 WAVES), 32 nodes (two 16-node groups). Grid = 625.
// Wave j owns ONE u-slice: r,z,in,hn for h-columns [16j, 16j+16).
// TWO-PASS gates: pass1 r,z (4 accs) -> sigmoid -> 16 scalars; pass2 in,hn
// (4 accs) -> epilogue. h-side MFMAs skipped at t=0 (h==0, exact).
// Accs never exceed 16 VGPRs; B-frags 4 in flight; A-frags from LDS.
// A-frag: row=lane&15 (node in group), k=(lane>>4)*8 per K=32 chunk.
// C/D layout (verified): row=(lane>>4)*4+reg, col=lane&15.
// ---------------------------------------------------------------------------
__global__ __launch_bounds__(512, 2) void k_gru_fused(
    const float* __restrict__ v, const int* __restrict__ widx,
    const short* __restrict__ Wihb, const short* __restrict__ Whhb,
    const short* __restrict__ WoutTb,
    const float* __restrict__ bih, const float* __restrict__ bhh,
    const float* __restrict__ bout, float* __restrict__ out)
{
    __shared__ short x_bf[32][136];
    __shared__ short h_bf[32][136];
    int tid = threadIdx.x;
    int j = tid >> 6, lane = tid & 63;      // wave j = u-slice j (0..7)
    int c = lane & 15, q = lane >> 4;
    int nb = blockIdx.x * 32;
    int u = j * 16 + c;

    // biases for this wave's slice
    float b_r  = bih[u] + bhh[u];
    float b_z  = bih[128 + u] + bhh[128 + u];
    float b_in = bih[256 + u];
    float b_hn = bhh[256 + u];

    float h_reg[2][4];            // [group][i]: h[row=q*4+i][col=u]
#pragma unroll
    for (int g = 0; g < 2; ++g)
#pragma unroll
        for (int i = 0; i < 4; ++i) h_reg[g][i] = 0.f;

    const short* bi_base = Wihb + c * 128 + q * 8 + j * 2048;
    const short* bh_base = Whhb + c * 128 + q * 8 + j * 2048;

#pragma unroll 1
    for (int t = 0; t < 1 + TSTEPS; ++t) {
        // ---- gather x_t -> bf16 LDS: 512 threads = 32 rows x 16 chunks ----
        {
            int row = tid >> 4, chunk = tid & 15;
            int src = widx[t * NN + nb + row];
            const float4* vp = (const float4*)(v + (size_t)src * 128 + chunk * 8);
            float4 a = vp[0], b = vp[1];
            s16x8 xv;
            xv[0] = f2bf(a.x); xv[1] = f2bf(a.y); xv[2] = f2bf(a.z); xv[3] = f2bf(a.w);
            xv[4] = f2bf(b.x); xv[5] = f2bf(b.y); xv[6] = f2bf(b.z); xv[7] = f2bf(b.w);
            *(s16x8*)&x_bf[row][chunk * 8] = xv;
        }
        __syncthreads();

        float rr[2][4], zz[2][4];

        // ---- pass 1: r and z accumulate (4 accs live) ----
        {
            f32x4 zf = {0.f, 0.f, 0.f, 0.f};
            f32x4 aR[2] = {zf, zf}, aZ[2] = {zf, zf};
#pragma unroll
            for (int ks = 0; ks < 4; ++ks) {
                s16x8 biR = *(const s16x8*)(bi_base + ks * 32);
                s16x8 biZ = *(const s16x8*)(bi_base + 8 * 2048 + ks * 32);
#pragma unroll
                for (int g = 0; g < 2; ++g) {
                    s16x8 a = *(const s16x8*)&x_bf[g * 16 + c][ks * 32 + q * 8];
                    aR[g] = MFMA16(a, biR, aR[g]);
                    aZ[g] = MFMA16(a, biZ, aZ[g]);
                }
            }
            if (t > 0) {
#pragma unroll
                for (int ks = 0; ks < 4; ++ks) {
                    s16x8 bhR = *(const s16x8*)(bh_base + ks * 32);
                    s16x8 bhZ = *(const s16x8*)(bh_base + 8 * 2048 + ks * 32);
#pragma unroll
                    for (int g = 0; g < 2; ++g) {
                        s16x8 a = *(const s16x8*)&h_bf[g * 16 + c][ks * 32 + q * 8];
                        aR[g] = MFMA16(a, bhR, aR[g]);
                        aZ[g] = MFMA16(a, bhZ, aZ[g]);
                    }
                }
            }
#pragma unroll
            for (int g = 0; g < 2; ++g)
#pragma unroll
                for (int i = 0; i < 4; ++i) {
                    rr[g][i] = 1.f / (1.f + expf(-(aR[g][i] + b_r)));
                    zz[g][i] = 1.f / (1.f + expf(-(aZ[g][i] + b_z)));
                }
        }

        // ---- pass 2: in and hn accumulate (4 accs live), then epilogue ----
        {
            f32x4 zf = {0.f, 0.f, 0.f, 0.f};
            f32x4 aIN[2] = {zf, zf}, aHN[2] = {zf, zf};
#pragma unroll
            for (int ks = 0; ks < 4; ++ks) {
                s16x8 biN = *(const s16x8*)(bi_base + 16 * 2048 + ks * 32);
#pragma unroll
                for (int g = 0; g < 2; ++g) {
                    s16x8 a = *(const s16x8*)&x_bf[g * 16 + c][ks * 32 + q * 8];
                    aIN[g] = MFMA16(a, biN, aIN[g]);
                }
            }
            if (t > 0) {
#pragma unroll
                for (int ks = 0; ks < 4; ++ks) {
                    s16x8 bhN = *(const s16x8*)(bh_base + 16 * 2048 + ks * 32);
#pragma unroll
                    for (int g = 0; g < 2; ++g) {
                        s16x8 a = *(const s16x8*)&h_bf[g * 16 + c][ks * 32 + q * 8];
                        aHN[g] = MFMA16(a, bhN, aHN[g]);
                    }
                }
            }
            // barrier BEFORE overwriting h_bf (pass-1/2 readers are done only
            // after all waves finish their MFMA reads of h_bf)
            __syncthreads();
#pragma unroll
            for (int g = 0; g < 2; ++g)
#pragma unroll
                for (int i = 0; i < 4; ++i) {
                    float ng = tanhf(aIN[g][i] + b_in + rr[g][i] * (aHN[g][i] + b_hn));
                    float hn = (1.f - zz[g][i]) * ng + zz[g][i] * h_reg[g][i];
                    h_reg[g][i] = hn;
                    h_bf[g * 16 + q * 4 + i][u] = f2bf(hn);
                }
        }
        __syncthreads();
    }

    // ---- output projection: wave j handles o-tile j (cols 16j..16j+15) ----
    {
        const short* bo_base = WoutTb + c * 128 + q * 8 + j * 2048;
        f32x4 zf = {0.f, 0.f, 0.f, 0.f};
        f32x4 acco[2] = {zf, zf};
#pragma unroll
        for (int ks = 0; ks < 4; ++ks) {
            s16x8 bo = *(const s16x8*)(bo_base + ks * 32);
#pragma unroll
            for (int g = 0; g < 2; ++g) {
                s16x8 a = *(const s16x8*)&h_bf[g * 16 + c][ks * 32 + q * 8];
                acco[g] = MFMA16(a, bo, acco[g]);
            }
        }
        float bb = bout[u];
#pragma unroll
        for (int g = 0; g < 2; ++g)
#pragma unroll
            for (int i = 0; i < 4; ++i)
                out[(size_t)(nb + g * 16 + q * 4 + i) * 128 + u] = acco[g][i] + bb;
    }
}

// ---------------------------------------------------------------------------
extern "C" void kernel_launch(void* const* d_in, const int* in_sizes, int n_in,
                              void* d_out, int out_size, void* d_ws, size_t ws_size,
                              hipStream_t stream)
{
    const float* node_attr = (const float*)d_in[0];
    const int*   edge_index = (const int*)d_in[1];
    const float* W1  = (const float*)d_in[3];
    const float* b1  = (const float*)d_in[4];
    const float* W2  = (const float*)d_in[5];
    const float* b2  = (const float*)d_in[6];
    const float* Wih = (const float*)d_in[7];
    const float* Whh = (const float*)d_in[8];
    const float* bih = (const float*)d_in[9];
    const float* bhh = (const float*)d_in[10];
    const float* Wout = (const float*)d_in[11];
    const float* bout = (const float*)d_in[12];
    const float* noise = (const float*)d_in[13];

    const int* dst = edge_index + (size_t)NN * DEGV;

    char* ws = (char*)d_ws;
    size_t offP    = 0;                               // 4*N*64 f32 = 20.48 MB
    size_t offBase = offP + (size_t)4 * NN * 64 * 4;  // N*64 f32   =  5.12 MB
    size_t offW    = offBase + (size_t)NN * 64 * 4;   // bf16 weights
    size_t offWidx = offW + (size_t)(2 * 49152 + 16384) * 2;
    float* P    = (float*)(ws + offP);
    float* base = (float*)(ws + offBase);
    short* Wihb   = (short*)(ws + offW);              // 384*128*2 = 96 KB
    short* Whhb   = Wihb + 384 * 128;
    short* WoutTb = Whhb + 384 * 128;                 // 128*128*2 = 32 KB
    int*   widx = (int*)(ws + offWidx);               // 4*N int

    dim3 blk(256);
    k_convert_w<<<dim3(448), blk, 0, stream>>>(Wih, Whh, Wout, Wihb, Whhb, WoutTb);
    k_precompute<<<dim3(1250), blk, 0, stream>>>(node_attr, W1, b1, P, base, widx);
    for (int t = 0; t < TSTEPS; ++t)
        k_walk_step<<<dim3(5000), blk, 0, stream>>>(P, base, dst, W2, b2, noise, widx, t);
    k_gru_fused<<<dim3(625), dim3(512), 0, stream>>>(node_attr, widx, Wihb, Whhb, WoutTb,
                                                     bih, bhh, bout, (float*)d_out);
}

// Round 9
// 166.251 us; speedup vs baseline: 1.6943x; 1.3357x over previous
//
#include <hip/hip_runtime.h>
#include <hip/hip_bf16.h>
#include <math.h>

#define NN 20000
#define DEGV 16
#define CINV 128
#define TSTEPS 3
#define HIDV 128

typedef float f32x4 __attribute__((ext_vector_type(4)));
typedef short s16x8 __attribute__((ext_vector_type(8)));

#define MFMA16(a, b, c) __builtin_amdgcn_mfma_f32_16x16x32_bf16(a, b, c, 0, 0, 0)

static __device__ __forceinline__ short f2bf(float x) {
    __hip_bfloat16 h = __float2bfloat16(x);
    return *reinterpret_cast<short*>(&h);
}

// ---------------------------------------------------------------------------
// Kernel 1: P[s][n][j] = sum_k v[n][k] * W1[(s*128+k)*64 + j]   (slot-major)
// 32 nodes/block (grid 625, exact). Thread tile: 8 nl x 4 j registers.
// Inner 16-k chains in f32, promoted to f64 outer sums (error ~5e-8, below
// numpy's own pairwise rounding -> argmax decisions unaffected).
// Also: emits vb (bf16 copy of v) and inits base / walk_idx[0].
// ---------------------------------------------------------------------------
__global__ __launch_bounds__(256) void k_precompute(
    const float* __restrict__ v, const float* __restrict__ W1,
    const float* __restrict__ b1,
    float* __restrict__ P, float* __restrict__ base, int* __restrict__ walk_idx,
    short* __restrict__ vb)
{
    __shared__ float vt[32][129];   // stride 129 words: ng-rows (8 apart) land in distinct banks
    int nb = blockIdx.x * 32;
    for (int idx = threadIdx.x; idx < 32 * 128; idx += 256) {
        int nl = idx >> 7, k = idx & 127;
        float x = v[(size_t)(nb + nl) * 128 + k];
        vt[nl][k] = x;
        vb[(size_t)(nb + nl) * 128 + k] = f2bf(x);
    }
    __syncthreads();

    int s  = threadIdx.x >> 6;          // 0..3 slot
    int jg = (threadIdx.x >> 2) & 15;   // 0..15 (j = jg + 16m)
    int ng = threadIdx.x & 3;           // 0..3  (nl = ng*8 + i)

    double accd[8][4];
#pragma unroll
    for (int i = 0; i < 8; ++i)
#pragma unroll
        for (int m = 0; m < 4; ++m) accd[i][m] = 0.0;

    const float* w1s = W1 + (size_t)s * 128 * 64 + jg;

    for (int kb = 0; kb < 8; ++kb) {
        float acc[8][4];
#pragma unroll
        for (int i = 0; i < 8; ++i)
#pragma unroll
            for (int m = 0; m < 4; ++m) acc[i][m] = 0.f;
#pragma unroll
        for (int kk = 0; kk < 16; ++kk) {
            int k = kb * 16 + kk;
            float w0 = w1s[k * 64 +  0];
            float w1 = w1s[k * 64 + 16];
            float w2 = w1s[k * 64 + 32];
            float w3 = w1s[k * 64 + 48];
#pragma unroll
            for (int i = 0; i < 8; ++i) {
                float xv = vt[ng * 8 + i][k];
                acc[i][0] = fmaf(xv, w0, acc[i][0]);
                acc[i][1] = fmaf(xv, w1, acc[i][1]);
                acc[i][2] = fmaf(xv, w2, acc[i][2]);
                acc[i][3] = fmaf(xv, w3, acc[i][3]);
            }
        }
#pragma unroll
        for (int i = 0; i < 8; ++i)
#pragma unroll
            for (int m = 0; m < 4; ++m) accd[i][m] += (double)acc[i][m];
    }

#pragma unroll
    for (int i = 0; i < 8; ++i) {
        int n = nb + ng * 8 + i;
#pragma unroll
        for (int m = 0; m < 4; ++m) {
            int j = jg + 16 * m;
            float pv = (float)accd[i][m];
            P[(size_t)s * NN * 64 + (size_t)n * 64 + j] = pv;
            if (s == 0) {
                base[(size_t)n * 64 + j] = pv + b1[j];
                if (j == 0) walk_idx[n] = n;
            }
        }
    }
}

// ---------------------------------------------------------------------------
// Kernel 2: one walk selection step. One 64-lane wave per node. (unchanged)
// ---------------------------------------------------------------------------
__global__ __launch_bounds__(256) void k_walk_step(
    const float* __restrict__ P, float* __restrict__ base,
    const int* __restrict__ dst, const float* __restrict__ W2,
    const float* __restrict__ b2, const float* __restrict__ noise,
    int* __restrict__ walk_idx, int t)
{
    int wave = threadIdx.x >> 6;
    int lane = threadIdx.x & 63;
    int n = blockIdx.x * 4 + wave;
    if (n >= NN) return;

    int wl = walk_idx[t * NN + n];
    int d = lane >> 2, sub = lane & 3;
    int cand = dst[wl * DEGV + d];

    const float* Pslice = P + (size_t)(t + 1) * NN * 64;
    const float4* b4 = (const float4*)(base + (size_t)n * 64);
    const float4* p4 = (const float4*)(Pslice + (size_t)cand * 64);
    const float4* w4 = (const float4*)W2;

    double acc = 0.0;
#pragma unroll
    for (int k = 0; k < 4; ++k) {
        float4 bb = b4[sub * 4 + k];
        float4 pp = p4[sub * 4 + k];
        float4 ww = w4[sub * 4 + k];
        acc += (double)fmaxf(bb.x + pp.x, 0.f) * (double)ww.x;
        acc += (double)fmaxf(bb.y + pp.y, 0.f) * (double)ww.y;
        acc += (double)fmaxf(bb.z + pp.z, 0.f) * (double)ww.z;
        acc += (double)fmaxf(bb.w + pp.w, 0.f) * (double)ww.w;
    }
    acc += __shfl_xor(acc, 1);
    acc += __shfl_xor(acc, 2);
    double logp = acc + (double)b2[0];

    double m = logp;
    for (int mask = 4; mask < 64; mask <<= 1) m = fmax(m, __shfl_xor(m, mask));
    double e = exp(logp - m);
    double ssum = e;
    for (int mask = 4; mask < 64; mask <<= 1) ssum += __shfl_xor(ssum, mask);
    double norm = m + log(ssum);

    double wp = exp(logp - norm) +
                0.01 * (double)noise[((size_t)t * NN + n) * DEGV + d];

    int bd = d;
    double bwp = wp;
    for (int mask = 4; mask < 64; mask <<= 1) {
        double owp = __shfl_xor(bwp, mask);
        int od = __shfl_xor(bd, mask);
        if (owp > bwp || (owp == bwp && od < bd)) { bwp = owp; bd = od; }
    }
    int sel = dst[wl * DEGV + bd];

    base[(size_t)n * 64 + lane] += Pslice[(size_t)sel * 64 + lane];
    if (lane == 0) walk_idx[(t + 1) * NN + n] = sel;
}

// ---------------------------------------------------------------------------
// Kernel 3: convert weights to bf16 (Wih, Whh row-major; Wout transposed)
// ---------------------------------------------------------------------------
__global__ __launch_bounds__(256) void k_convert_w(
    const float* __restrict__ Wih, const float* __restrict__ Whh,
    const float* __restrict__ Wout,
    short* __restrict__ Wihb, short* __restrict__ Whhb, short* __restrict__ WoutTb)
{
    int idx = blockIdx.x * 256 + threadIdx.x;
    if (idx < 49152) {
        Wihb[idx] = f2bf(Wih[idx]);
    } else if (idx < 98304) {
        int e = idx - 49152;
        Whhb[e] = f2bf(Whh[e]);
    } else if (idx < 114688) {
        int e = idx - 98304;
        int o = e >> 7, k = e & 127;
        WoutTb[e] = f2bf(Wout[k * 128 + o]);   // WoutT[o][k]
    }
}

// ---------------------------------------------------------------------------
// Kernel 4: fused GRU (4 steps) + output projection, MFMA bf16.
// Block = 512 threads (8 waves), 32 nodes. Grid = 625, (512,4): all resident.
// Wave j owns one u-slice (cols 16j..16j+15); two-pass gates (r,z then n).
// Gather is a raw bf16 16B copy (v pre-converted). Fast __expf gate math.
// A-frag: row=lane&15, k=(lane>>4)*8 per K=32 chunk.
// C/D layout (verified): row=(lane>>4)*4+reg, col=lane&15.
// ---------------------------------------------------------------------------
__global__ __launch_bounds__(512, 4) void k_gru_fused(
    const short* __restrict__ vb, const int* __restrict__ widx,
    const short* __restrict__ Wihb, const short* __restrict__ Whhb,
    const short* __restrict__ WoutTb,
    const float* __restrict__ bih, const float* __restrict__ bhh,
    const float* __restrict__ bout, float* __restrict__ out)
{
    __shared__ short x_bf[32][136];
    __shared__ short h_bf[32][136];
    int tid = threadIdx.x;
    int j = tid >> 6, lane = tid & 63;      // wave j = u-slice j (0..7)
    int c = lane & 15, q = lane >> 4;
    int nb = blockIdx.x * 32;
    int u = j * 16 + c;

    float b_r  = bih[u] + bhh[u];
    float b_z  = bih[128 + u] + bhh[128 + u];
    float b_in = bih[256 + u];
    float b_hn = bhh[256 + u];

    float h_reg[2][4];
#pragma unroll
    for (int g = 0; g < 2; ++g)
#pragma unroll
        for (int i = 0; i < 4; ++i) h_reg[g][i] = 0.f;

    const short* bi_base = Wihb + c * 128 + q * 8 + j * 2048;
    const short* bh_base = Whhb + c * 128 + q * 8 + j * 2048;

#pragma unroll 1
    for (int t = 0; t < 1 + TSTEPS; ++t) {
        // ---- gather x_t -> bf16 LDS: pure 16B copy, 512 thr = 32 rows x 16 chunks ----
        {
            int row = tid >> 4, chunk = tid & 15;
            int src = widx[t * NN + nb + row];
            *(s16x8*)&x_bf[row][chunk * 8] =
                *(const s16x8*)(vb + (size_t)src * 128 + chunk * 8);
        }
        __syncthreads();

        float rr[2][4], zz[2][4];

        // ---- pass 1: r and z ----
        {
            f32x4 zf = {0.f, 0.f, 0.f, 0.f};
            f32x4 aR[2] = {zf, zf}, aZ[2] = {zf, zf};
#pragma unroll
            for (int ks = 0; ks < 4; ++ks) {
                s16x8 biR = *(const s16x8*)(bi_base + ks * 32);
                s16x8 biZ = *(const s16x8*)(bi_base + 8 * 2048 + ks * 32);
#pragma unroll
                for (int g = 0; g < 2; ++g) {
                    s16x8 a = *(const s16x8*)&x_bf[g * 16 + c][ks * 32 + q * 8];
                    aR[g] = MFMA16(a, biR, aR[g]);
                    aZ[g] = MFMA16(a, biZ, aZ[g]);
                }
            }
            if (t > 0) {
#pragma unroll
                for (int ks = 0; ks < 4; ++ks) {
                    s16x8 bhR = *(const s16x8*)(bh_base + ks * 32);
                    s16x8 bhZ = *(const s16x8*)(bh_base + 8 * 2048 + ks * 32);
#pragma unroll
                    for (int g = 0; g < 2; ++g) {
                        s16x8 a = *(const s16x8*)&h_bf[g * 16 + c][ks * 32 + q * 8];
                        aR[g] = MFMA16(a, bhR, aR[g]);
                        aZ[g] = MFMA16(a, bhZ, aZ[g]);
                    }
                }
            }
#pragma unroll
            for (int g = 0; g < 2; ++g)
#pragma unroll
                for (int i = 0; i < 4; ++i) {
                    rr[g][i] = 1.f / (1.f + __expf(-(aR[g][i] + b_r)));
                    zz[g][i] = 1.f / (1.f + __expf(-(aZ[g][i] + b_z)));
                }
        }

        // ---- pass 2: in and hn, then epilogue ----
        {
            f32x4 zf = {0.f, 0.f, 0.f, 0.f};
            f32x4 aIN[2] = {zf, zf}, aHN[2] = {zf, zf};
#pragma unroll
            for (int ks = 0; ks < 4; ++ks) {
                s16x8 biN = *(const s16x8*)(bi_base + 16 * 2048 + ks * 32);
#pragma unroll
                for (int g = 0; g < 2; ++g) {
                    s16x8 a = *(const s16x8*)&x_bf[g * 16 + c][ks * 32 + q * 8];
                    aIN[g] = MFMA16(a, biN, aIN[g]);
                }
            }
            if (t > 0) {
#pragma unroll
                for (int ks = 0; ks < 4; ++ks) {
                    s16x8 bhN = *(const s16x8*)(bh_base + 16 * 2048 + ks * 32);
#pragma unroll
                    for (int g = 0; g < 2; ++g) {
                        s16x8 a = *(const s16x8*)&h_bf[g * 16 + c][ks * 32 + q * 8];
                        aHN[g] = MFMA16(a, bhN, aHN[g]);
                    }
                }
            }
            __syncthreads();   // all h_bf reads done before overwrite
#pragma unroll
            for (int g = 0; g < 2; ++g)
#pragma unroll
                for (int i = 0; i < 4; ++i) {
                    float narg = aIN[g][i] + b_in + rr[g][i] * (aHN[g][i] + b_hn);
                    float e2 = __expf(2.f * narg);
                    float ngt = 1.f - 2.f / (e2 + 1.f);    // tanh, exact at saturation
                    float hn = (1.f - zz[g][i]) * ngt + zz[g][i] * h_reg[g][i];
                    h_reg[g][i] = hn;
                    h_bf[g * 16 + q * 4 + i][u] = f2bf(hn);
                }
        }
        __syncthreads();
    }

    // ---- output projection: wave j handles o-tile j ----
    {
        const short* bo_base = WoutTb + c * 128 + q * 8 + j * 2048;
        f32x4 zf = {0.f, 0.f, 0.f, 0.f};
        f32x4 acco[2] = {zf, zf};
#pragma unroll
        for (int ks = 0; ks < 4; ++ks) {
            s16x8 bo = *(const s16x8*)(bo_base + ks * 32);
#pragma unroll
            for (int g = 0; g < 2; ++g) {
                s16x8 a = *(const s16x8*)&h_bf[g * 16 + c][ks * 32 + q * 8];
                acco[g] = MFMA16(a, bo, acco[g]);
            }
        }
        float bb = bout[u];
#pragma unroll
        for (int g = 0; g < 2; ++g)
#pragma unroll
            for (int i = 0; i < 4; ++i)
                out[(size_t)(nb + g * 16 + q * 4 + i) * 128 + u] = acco[g][i] + bb;
    }
}

// ---------------------------------------------------------------------------
extern "C" void kernel_launch(void* const* d_in, const int* in_sizes, int n_in,
                              void* d_out, int out_size, void* d_ws, size_t ws_size,
                              hipStream_t stream)
{
    const float* node_attr = (const float*)d_in[0];
    const int*   edge_index = (const int*)d_in[1];
    const float* W1  = (const float*)d_in[3];
    const float* b1  = (const float*)d_in[4];
    const float* W2  = (const float*)d_in[5];
    const float* b2  = (const float*)d_in[6];
    const float* Wih = (const float*)d_in[7];
    const float* Whh = (const float*)d_in[8];
    const float* bih = (const float*)d_in[9];
    const float* bhh = (const float*)d_in[10];
    const float* Wout = (const float*)d_in[11];
    const float* bout = (const float*)d_in[12];
    const float* noise = (const float*)d_in[13];

    const int* dst = edge_index + (size_t)NN * DEGV;

    char* ws = (char*)d_ws;
    size_t offP    = 0;                               // 4*N*64 f32 = 20.48 MB
    size_t offBase = offP + (size_t)4 * NN * 64 * 4;  // N*64 f32   =  5.12 MB
    size_t offW    = offBase + (size_t)NN * 64 * 4;   // bf16 weights 0.23 MB
    size_t offWidx = offW + (size_t)(2 * 49152 + 16384) * 2;
    size_t offVb   = offWidx + (size_t)4 * NN * 4;    // bf16 v = 5.12 MB
    float* P    = (float*)(ws + offP);
    float* base = (float*)(ws + offBase);
    short* Wihb   = (short*)(ws + offW);
    short* Whhb   = Wihb + 384 * 128;
    short* WoutTb = Whhb + 384 * 128;
    int*   widx = (int*)(ws + offWidx);
    short* vb   = (short*)(ws + offVb);

    dim3 blk(256);
    k_convert_w<<<dim3(448), blk, 0, stream>>>(Wih, Whh, Wout, Wihb, Whhb, WoutTb);
    k_precompute<<<dim3(625), blk, 0, stream>>>(node_attr, W1, b1, P, base, widx, vb);
    for (int t = 0; t < TSTEPS; ++t)
        k_walk_step<<<dim3(5000), blk, 0, stream>>>(P, base, dst, W2, b2, noise, widx, t);
    k_gru_fused<<<dim3(625), dim3(512), 0, stream>>>(vb, widx, Wihb, Whhb, WoutTb,
                                                     bih, bhh, bout, (float*)d_out);
}